// Round 4
// baseline (11268.087 us; speedup 1.0000x reference)
//
#include <hip/hip_runtime.h>
#include <math.h>

#define NBLOCKS 512
#define NTHREADS 256
#define WPB 4                 // waves per block
#define HDIM 4096
#define NPAIR (HDIM/2)        // 2048 f16x2 pairs

typedef _Float16 f16x2 __attribute__((ext_vector_type(2)));
typedef _Float16 f16x8 __attribute__((ext_vector_type(8)));
typedef unsigned long long u64;

union UF { unsigned u; f16x2 h; };

__device__ __forceinline__ float dot2f(f16x2 a, f16x2 b, float c) {
  return __builtin_amdgcn_fdot2(a, b, c, false);   // v_dot2_f32_f16
}
__device__ __forceinline__ float sigmoidf_(float x) {
  return 1.0f / (1.0f + __expf(-x));
}
__device__ __forceinline__ float tanhf_(float x) {
  float a = fabsf(x);
  float t = __expf(-2.0f * a);
  float r = (1.0f - t) / (1.0f + t);
  return copysignf(r, x);
}
__device__ __forceinline__ void st64(u64* p, u64 v) {
  __hip_atomic_store(p, v, __ATOMIC_RELAXED, __HIP_MEMORY_SCOPE_AGENT);
}
__device__ __forceinline__ u64 ld64(const u64* p) {
  return __hip_atomic_load(p, __ATOMIC_RELAXED, __HIP_MEMORY_SCOPE_AGENT);
}

// ---- one f16x8 chunk = 4 f16x2 pairs; pair j of chunk C at (float2*)SRC + lane + 64*(4C+j) ----
#define LOAD_CHUNK8(VAR, SRC, C) do {                                         \
  const float2* s_ = (const float2*)(SRC) + lane + 64 * (4 * (C));            \
  float2 p0_ = s_[0]; float2 p1_ = s_[64]; float2 p2_ = s_[128]; float2 p3_ = s_[192]; \
  VAR = (f16x8){ (_Float16)p0_.x, (_Float16)p0_.y, (_Float16)p1_.x, (_Float16)p1_.y, \
                 (_Float16)p2_.x, (_Float16)p2_.y, (_Float16)p3_.x, (_Float16)p3_.y }; \
} while (0)

#define DECL_ROW(K) f16x8 w##K##_0, w##K##_1, w##K##_2, w##K##_3,             \
                          w##K##_4, w##K##_5, w##K##_6, w##K##_7;

#define LOAD_ROW(K, GATE, IDX) do {                                           \
  const float* sr_ = W_hh + ((size_t)(GATE) * HDIM + (i0 + (IDX))) * HDIM;    \
  LOAD_CHUNK8(w##K##_0, sr_, 0); LOAD_CHUNK8(w##K##_1, sr_, 1);               \
  LOAD_CHUNK8(w##K##_2, sr_, 2); LOAD_CHUNK8(w##K##_3, sr_, 3);               \
  LOAD_CHUNK8(w##K##_4, sr_, 4); LOAD_CHUNK8(w##K##_5, sr_, 5);               \
  LOAD_CHUNK8(w##K##_6, sr_, 6); LOAD_CHUNK8(w##K##_7, sr_, 7);               \
} while (0)

#define PAIR8(V, J) (__builtin_shufflevector((V), (V), 2 * (J), 2 * (J) + 1))

#define DOT4(K, C)                                                            \
  a##K = dot2f(PAIR8(w##K##_##C, 0), hp0, a##K);                              \
  a##K = dot2f(PAIR8(w##K##_##C, 1), hp1, a##K);                              \
  a##K = dot2f(PAIR8(w##K##_##C, 2), hp2, a##K);                              \
  a##K = dot2f(PAIR8(w##K##_##C, 3), hp3, a##K);

#define CHUNK_STEP(C) {                                                       \
  UF u0_, u1_, u2_, u3_;                                                      \
  u0_.u = h_lds[lane + 64 * (4 * (C) + 0)];                                   \
  u1_.u = h_lds[lane + 64 * (4 * (C) + 1)];                                   \
  u2_.u = h_lds[lane + 64 * (4 * (C) + 2)];                                   \
  u3_.u = h_lds[lane + 64 * (4 * (C) + 3)];                                   \
  f16x2 hp0 = u0_.h, hp1 = u1_.h, hp2 = u2_.h, hp3 = u3_.h;                   \
  DOT4(0, C) DOT4(1, C) DOT4(2, C) DOT4(3, C) DOT4(4, C) DOT4(5, C)          \
}

#define GX_INIT(K, GATE, IDX) {                                               \
  const int row_ = (GATE) * HDIM + (i0 + (IDX));                              \
  const float* s_ = W_ih + (size_t)row_ * 400;                                \
  float acc_ = 0.0f;                                                          \
  for (int c = lane; c < 400; c += 64) acc_ += s_[c] * x_lds[c];              \
  _Pragma("unroll")                                                           \
  for (int o_ = 32; o_; o_ >>= 1) acc_ += __shfl_xor(acc_, o_, 64);           \
  acc_ += b_ih[row_];                                                         \
  if ((GATE) != 2) acc_ += b_hh[row_];                                        \
  gx##K = acc_;                                                               \
}

// 512 blocks x 256 threads (4 waves). 2 waves/SIMD, VGPR cap 256.
// Wave G (0..2047) owns h indices {2G, 2G+1} = 6 W_hh rows = 192 weight VGPRs.
__global__ __launch_bounds__(NTHREADS, 2)
void gru_persistent(const float* __restrict__ start,
                    const float* __restrict__ enc_h,
                    const float* __restrict__ W_ih,
                    const float* __restrict__ W_hh,
                    const float* __restrict__ b_ih,
                    const float* __restrict__ b_hh,
                    const float* __restrict__ W_out,
                    const float* __restrict__ b_out,
                    float* __restrict__ out,
                    u64* __restrict__ ws,
                    int T)
{
  __shared__ unsigned h_lds[NPAIR];          // h_t as f16x2 pairs (8 KB)
  __shared__ unsigned wout_lds[NPAIR];       // this block's W_out row, f16x2 (8 KB)
  __shared__ float    x_lds[400];            // relu(start)

  const int tid  = threadIdx.x;
  const int b    = blockIdx.x;
  const int wave = tid >> 6;
  const int lane = tid & 63;
  const int G    = b * WPB + wave;           // global wave id, 0..2047
  const int i0   = 2 * G;                    // first owned h index

  u64* buf0 = ws;            // [NPAIR] tagged h pairs, even steps
  u64* buf1 = ws + NPAIR;    // odd steps
  // tag for h_t is (t+1); 0xAA poison word (0xAAAAAAAA) never equals a valid tag.

  // ---- stage x = relu(start) and this block's W_out row (f16) into LDS ----
  for (int p = tid; p < 400; p += NTHREADS) x_lds[p] = fmaxf(start[p], 0.0f);
  if (b < 401) {
    for (int p = tid; p < NPAIR; p += NTHREADS) {
      float2 wv = *(const float2*)(W_out + (size_t)b * HDIM + 2 * p);
      UF u; u.h = (f16x2){(_Float16)wv.x, (_Float16)wv.y};
      wout_lds[p] = u.u;
    }
  }
  __syncthreads();

  // ---- persistent W_hh fragment: 6 rows x 8 chunks of f16x8 = 192 VGPRs ----
  DECL_ROW(0) DECL_ROW(1) DECL_ROW(2) DECL_ROW(3) DECL_ROW(4) DECL_ROW(5)
  LOAD_ROW(0, 0, 0); LOAD_ROW(1, 0, 1);   // r
  LOAD_ROW(2, 1, 0); LOAD_ROW(3, 1, 1);   // z
  LOAD_ROW(4, 2, 0); LOAD_ROW(5, 2, 1);   // n

  // ---- gx = W_ih @ relu(start) + b_ih (+ b_hh folded for r,z) ----
  float gx0, gx1, gx2, gx3, gx4, gx5;
  GX_INIT(0, 0, 0); GX_INIT(1, 0, 1);
  GX_INIT(2, 1, 0); GX_INIT(3, 1, 1);
  GX_INIT(4, 2, 0); GX_INIT(5, 2, 1);
  const float bhn0 = b_hh[2 * HDIM + i0];
  const float bhn1 = b_hh[2 * HDIM + i0 + 1];

  // ---- h carry (fp32, owner registers) ----
  float h0 = enc_h[i0], h1 = enc_h[i0 + 1];

  // publish h_0 (tag 1): wave G owns exchange slot G
  if (lane == 0) {
    UF u; u.h = (f16x2){(_Float16)h0, (_Float16)h1};
    st64(&buf0[G], ((u64)1u << 32) | (u64)u.u);
  }

  // ---- main scan ----
  for (int t = 0; t < T; ++t) {
    u64* rd = (t & 1) ? buf1 : buf0;   // holds h_t, tag t+1
    u64* wr = (t & 1) ? buf0 : buf1;   // gets h_{t+1}, tag t+2
    const unsigned exp = (unsigned)(t + 1);

    // phase 1: tagged spin + broadcast -> LDS (this IS the grid barrier)
    {
      const int p0 = tid;                 const int p1 = tid + NTHREADS;
      const int p2 = tid + 2 * NTHREADS;  const int p3 = tid + 3 * NTHREADS;
      const int p4 = tid + 4 * NTHREADS;  const int p5 = tid + 5 * NTHREADS;
      const int p6 = tid + 6 * NTHREADS;  const int p7 = tid + 7 * NTHREADS;
      u64 v0, v1, v2, v3, v4, v5, v6, v7;
      for (;;) {
        v0 = ld64(rd + p0); v1 = ld64(rd + p1);
        v2 = ld64(rd + p2); v3 = ld64(rd + p3);
        v4 = ld64(rd + p4); v5 = ld64(rd + p5);
        v6 = ld64(rd + p6); v7 = ld64(rd + p7);
        if ((unsigned)(v0 >> 32) == exp && (unsigned)(v1 >> 32) == exp &&
            (unsigned)(v2 >> 32) == exp && (unsigned)(v3 >> 32) == exp &&
            (unsigned)(v4 >> 32) == exp && (unsigned)(v5 >> 32) == exp &&
            (unsigned)(v6 >> 32) == exp && (unsigned)(v7 >> 32) == exp) break;
        __builtin_amdgcn_s_sleep(1);
      }
      h_lds[p0] = (unsigned)v0; h_lds[p1] = (unsigned)v1;
      h_lds[p2] = (unsigned)v2; h_lds[p3] = (unsigned)v3;
      h_lds[p4] = (unsigned)v4; h_lds[p5] = (unsigned)v5;
      h_lds[p6] = (unsigned)v6; h_lds[p7] = (unsigned)v7;
    }
    __syncthreads();

    // gh = W_hh @ h_t : 6 rows per wave, h pairs reused across rows
    float a0 = 0.f, a1 = 0.f, a2 = 0.f, a3 = 0.f, a4 = 0.f, a5 = 0.f;
    CHUNK_STEP(0); CHUNK_STEP(1); CHUNK_STEP(2); CHUNK_STEP(3);
    CHUNK_STEP(4); CHUNK_STEP(5); CHUNK_STEP(6); CHUNK_STEP(7);
    #pragma unroll
    for (int off = 32; off; off >>= 1) {
      a0 += __shfl_xor(a0, off, 64);
      a1 += __shfl_xor(a1, off, 64);
      a2 += __shfl_xor(a2, off, 64);
      a3 += __shfl_xor(a3, off, 64);
      a4 += __shfl_xor(a4, off, 64);
      a5 += __shfl_xor(a5, off, 64);
    }

    float r0 = sigmoidf_(gx0 + a0);
    float r1 = sigmoidf_(gx1 + a1);
    float z0 = sigmoidf_(gx2 + a2);
    float z1 = sigmoidf_(gx3 + a3);
    float n0 = tanhf_(gx4 + r0 * (a4 + bhn0));
    float n1 = tanhf_(gx5 + r1 * (a5 + bhn1));
    h0 = (1.0f - z0) * n0 + z0 * h0;
    h1 = (1.0f - z1) * n1 + z1 * h1;

    // publish h_{t+1} ASAP (tag t+2)
    if (lane == 0) {
      UF u; u.h = (f16x2){(_Float16)h0, (_Float16)h1};
      st64(&wr[G], ((u64)(unsigned)(t + 2) << 32) | (u64)u.u);
    }

    // output for step t-1 (uses h_t, still in LDS) — hides in others' spin
    if (t > 0 && wave == 0 && b < 401) {
      float acc = 0.0f;
      #pragma unroll
      for (int j = 0; j < 32; ++j) {
        int p = lane + 64 * j;
        UF a, hh; a.u = wout_lds[p]; hh.u = h_lds[p];
        acc = dot2f(a.h, hh.h, acc);
      }
      #pragma unroll
      for (int off = 32; off; off >>= 1) acc += __shfl_xor(acc, off, 64);
      if (lane == 0) {
        acc += b_out[b];
        if (b < 400) out[(size_t)(t - 1) * 400 + b] = tanhf_(acc);
        else         out[(size_t)400 * T + (t - 1)] = sigmoidf_(acc);
      }
    }
    __syncthreads();   // protect h_lds before next phase-1 overwrite
  }

  // ---- final output flush: o_{T-1} = W_out @ h_T (tag T+1) ----
  {
    u64* rd = (T & 1) ? buf1 : buf0;
    const unsigned exp = (unsigned)(T + 1);
    const int p0 = tid;                 const int p1 = tid + NTHREADS;
    const int p2 = tid + 2 * NTHREADS;  const int p3 = tid + 3 * NTHREADS;
    const int p4 = tid + 4 * NTHREADS;  const int p5 = tid + 5 * NTHREADS;
    const int p6 = tid + 6 * NTHREADS;  const int p7 = tid + 7 * NTHREADS;
    u64 v0, v1, v2, v3, v4, v5, v6, v7;
    for (;;) {
      v0 = ld64(rd + p0); v1 = ld64(rd + p1);
      v2 = ld64(rd + p2); v3 = ld64(rd + p3);
      v4 = ld64(rd + p4); v5 = ld64(rd + p5);
      v6 = ld64(rd + p6); v7 = ld64(rd + p7);
      if ((unsigned)(v0 >> 32) == exp && (unsigned)(v1 >> 32) == exp &&
          (unsigned)(v2 >> 32) == exp && (unsigned)(v3 >> 32) == exp &&
          (unsigned)(v4 >> 32) == exp && (unsigned)(v5 >> 32) == exp &&
          (unsigned)(v6 >> 32) == exp && (unsigned)(v7 >> 32) == exp) break;
      __builtin_amdgcn_s_sleep(1);
    }
    h_lds[p0] = (unsigned)v0; h_lds[p1] = (unsigned)v1;
    h_lds[p2] = (unsigned)v2; h_lds[p3] = (unsigned)v3;
    h_lds[p4] = (unsigned)v4; h_lds[p5] = (unsigned)v5;
    h_lds[p6] = (unsigned)v6; h_lds[p7] = (unsigned)v7;
    __syncthreads();
    if (wave == 0 && b < 401) {
      float acc = 0.0f;
      #pragma unroll
      for (int j = 0; j < 32; ++j) {
        int p = lane + 64 * j;
        UF a, hh; a.u = wout_lds[p]; hh.u = h_lds[p];
        acc = dot2f(a.h, hh.h, acc);
      }
      #pragma unroll
      for (int off = 32; off; off >>= 1) acc += __shfl_xor(acc, off, 64);
      if (lane == 0) {
        acc += b_out[b];
        if (b < 400) out[(size_t)(T - 1) * 400 + b] = tanhf_(acc);
        else         out[(size_t)400 * T + (T - 1)] = sigmoidf_(acc);
      }
    }
  }
}

extern "C" void kernel_launch(void* const* d_in, const int* in_sizes, int n_in,
                              void* d_out, int out_size, void* d_ws, size_t ws_size,
                              hipStream_t stream) {
  (void)in_sizes; (void)n_in; (void)ws_size;
  const float* start = (const float*)d_in[0];
  const float* enc_h = (const float*)d_in[1];
  const float* W_ih  = (const float*)d_in[2];
  const float* W_hh  = (const float*)d_in[3];
  const float* b_ih  = (const float*)d_in[4];
  const float* b_hh  = (const float*)d_in[5];
  const float* W_out = (const float*)d_in[6];
  const float* b_out = (const float*)d_in[7];
  float* out = (float*)d_out;
  u64* ws = (u64*)d_ws;

  int T = out_size / 401;   // outputs T*400 + stops T

  gru_persistent<<<NBLOCKS, NTHREADS, 0, stream>>>(
      start, enc_h, W_ih, W_hh, b_ih, b_hh, W_out, b_out, out, ws, T);
}